// Round 1
// baseline (160.824 us; speedup 1.0000x reference)
//
#include <hip/hip_runtime.h>
#include <hip/hip_bf16.h>
#include <stdint.h>

typedef short s8v __attribute__((ext_vector_type(8)));   // 8 bf16 (4 VGPRs)
typedef float f4v __attribute__((ext_vector_type(4)));   // MFMA C/D

static __device__ __forceinline__ uint16_t f2bf(float f) {
    union { float f; uint32_t u; } v; v.f = f;
    uint32_t r = v.u + 0x7fffu + ((v.u >> 16) & 1u);
    return (uint16_t)(r >> 16);
}

// ---------------------------------------------------------------------------
// Kernel 1: QKV projection.  x[16384][512] fp32 @ w[3][512][64] fp32
//   -> Q [b][s][64] bf16 (scaled by log2e/8), K [b][s][64] bf16, Vt [b][64][s] bf16
// 256 blocks x 256 threads; block computes 64 rows x 192 cols; K-loop step 32.
// ---------------------------------------------------------------------------
__global__ __launch_bounds__(256) void qkv_proj(const float* __restrict__ x,
                                                const float* __restrict__ w,
                                                uint16_t* __restrict__ qo,
                                                uint16_t* __restrict__ ko,
                                                uint16_t* __restrict__ vto) {
    __shared__ uint16_t xs[64][40];      // x tile, bf16, padded 32->40 (80B rows)
    __shared__ uint16_t ws[3][64][40];   // weight tile transposed [h][k], padded

    const int tid  = threadIdx.x;
    const int lane = tid & 63;
    const int wv   = tid >> 6;           // wave 0..3 -> 16-row slab
    const int row0 = blockIdx.x * 64;

    const int lr = lane & 15;
    const int lg = lane >> 4;

    f4v acc[12];
    #pragma unroll
    for (int i = 0; i < 12; ++i) acc[i] = (f4v){0.f, 0.f, 0.f, 0.f};

    const int xr = tid >> 2;             // 0..63 row
    const int xc = (tid & 3) * 8;        // 0,8,16,24
    const int wk = tid >> 3;             // 0..31 k-row
    const int wh = (tid & 7) * 8;        // 0..56 h

    for (int kb = 0; kb < 512; kb += 32) {
        // stage x tile (fp32 -> bf16)
        {
            const float* src = x + (size_t)(row0 + xr) * 512 + kb + xc;
            s8v v;
            #pragma unroll
            for (int j = 0; j < 8; ++j) v[j] = (short)f2bf(src[j]);
            *(s8v*)&xs[xr][xc] = v;
        }
        // stage weight tile transposed: ws[p][h][kk] = w[p][kb+kk][h]
        #pragma unroll
        for (int p = 0; p < 3; ++p) {
            const float* src = w + ((size_t)p * 512 + kb + wk) * 64 + wh;
            #pragma unroll
            for (int j = 0; j < 8; ++j) ws[p][wh + j][wk] = f2bf(src[j]);
        }
        __syncthreads();

        // A-frag: rows = this wave's 16 rows, k = lg*8..+7
        s8v a = *(const s8v*)&xs[wv * 16 + lr][lg * 8];
        #pragma unroll
        for (int nt = 0; nt < 12; ++nt) {
            const int p = nt >> 2, ht = nt & 3;
            s8v bfr = *(const s8v*)&ws[p][ht * 16 + lr][lg * 8];
            acc[nt] = __builtin_amdgcn_mfma_f32_16x16x32_bf16(a, bfr, acc[nt], 0, 0, 0);
        }
        __syncthreads();
    }

    // epilogue: D layout col = lane&15, row = (lane>>4)*4 + reg
    const float qscale = 0.18033688011112042f;   // log2(e) / sqrt(64)
    #pragma unroll
    for (int nt = 0; nt < 12; ++nt) {
        const int p = nt >> 2, ht = nt & 3;
        const int h = ht * 16 + lr;
        #pragma unroll
        for (int r = 0; r < 4; ++r) {
            const int row = row0 + wv * 16 + lg * 4 + r;
            const float val = acc[nt][r];
            if (p == 0)      qo[(size_t)row * 64 + h] = f2bf(val * qscale);
            else if (p == 1) ko[(size_t)row * 64 + h] = f2bf(val);
            else {
                const int bb = row >> 11, s = row & 2047;
                vto[((size_t)bb * 64 + h) * 2048 + s] = f2bf(val);
            }
        }
    }
}

// ---------------------------------------------------------------------------
// Kernel 2: flash attention.  Q,K [b][2048][64] bf16, Vt [b][64][2048] bf16
//   -> out [b][2048][64] fp32
// 256 blocks (b x qblock64) x 4 waves; wave owns 16 q rows; key blocks of 64.
// ---------------------------------------------------------------------------
__global__ __launch_bounds__(256) void attn(const uint16_t* __restrict__ q,
                                            const uint16_t* __restrict__ k,
                                            const uint16_t* __restrict__ vt,
                                            float* __restrict__ out) {
    __shared__ uint16_t plds[4][16][72];   // per-wave P^ tile [q][key], 144B rows

    const int tid  = threadIdx.x;
    const int lane = tid & 63;
    const int wv   = tid >> 6;
    const int b    = blockIdx.x >> 5;
    const int qblk = blockIdx.x & 31;
    const int qbase = qblk * 64 + wv * 16;

    const uint16_t* qb = q  + (size_t)b * 2048 * 64;
    const uint16_t* kp = k  + (size_t)b * 2048 * 64;
    const uint16_t* vb = vt + (size_t)b * 64 * 2048;

    const int lr = lane & 15;
    const int lg = lane >> 4;

    // Q fragments in registers (scale already folded in)
    s8v a0 = *(const s8v*)(qb + (size_t)(qbase + lr) * 64 + lg * 8);
    s8v a1 = *(const s8v*)(qb + (size_t)(qbase + lr) * 64 + 32 + lg * 8);

    f4v O[4];
    #pragma unroll
    for (int ht = 0; ht < 4; ++ht) O[ht] = (f4v){0.f, 0.f, 0.f, 0.f};
    float mrun[4], lrun[4];
    #pragma unroll
    for (int r = 0; r < 4; ++r) { mrun[r] = -3.0e38f; lrun[r] = 0.f; }

    // prefetch first K-block fragments
    s8v kf0[4], kf1[4];
    #pragma unroll
    for (int kt = 0; kt < 4; ++kt) {
        const uint16_t* kr = kp + (size_t)(kt * 16 + lr) * 64 + lg * 8;
        kf0[kt] = *(const s8v*)kr;
        kf1[kt] = *(const s8v*)(kr + 32);
    }

    for (int kb2 = 0; kb2 < 2048; kb2 += 64) {
        // V fragments for this key block (B: k=key, col=h) from Vt
        s8v vf0[4], vf1[4];
        #pragma unroll
        for (int ht = 0; ht < 4; ++ht) {
            const uint16_t* vr = vb + (size_t)(ht * 16 + lr) * 2048 + kb2 + lg * 8;
            vf0[ht] = *(const s8v*)vr;
            vf1[ht] = *(const s8v*)(vr + 32);
        }

        // S tile: S[q][key] for 16q x 64key
        f4v sacc[4];
        #pragma unroll
        for (int kt = 0; kt < 4; ++kt) {
            f4v z = (f4v){0.f, 0.f, 0.f, 0.f};
            z = __builtin_amdgcn_mfma_f32_16x16x32_bf16(a0, kf0[kt], z, 0, 0, 0);
            sacc[kt] = __builtin_amdgcn_mfma_f32_16x16x32_bf16(a1, kf1[kt], z, 0, 0, 0);
        }

        // prefetch next key block's K fragments
        if (kb2 + 64 < 2048) {
            #pragma unroll
            for (int kt = 0; kt < 4; ++kt) {
                const uint16_t* kr = kp + (size_t)(kb2 + 64 + kt * 16 + lr) * 64 + lg * 8;
                kf0[kt] = *(const s8v*)kr;
                kf1[kt] = *(const s8v*)(kr + 32);
            }
        }

        // ---- online softmax (rows spread over regs; cols over lanes 0..15) ----
        float rmax[4];
        #pragma unroll
        for (int r = 0; r < 4; ++r)
            rmax[r] = fmaxf(fmaxf(sacc[0][r], sacc[1][r]), fmaxf(sacc[2][r], sacc[3][r]));
        #pragma unroll
        for (int r = 0; r < 4; ++r) {
            #pragma unroll
            for (int m = 1; m < 16; m <<= 1)
                rmax[r] = fmaxf(rmax[r], __shfl_xor(rmax[r], m, 64));
        }
        float sc[4];
        #pragma unroll
        for (int r = 0; r < 4; ++r) {
            const float mn = fmaxf(mrun[r], rmax[r]);
            sc[r] = exp2f(mrun[r] - mn);
            mrun[r] = mn;
        }
        float p[4][4], rsum[4];
        #pragma unroll
        for (int kt = 0; kt < 4; ++kt)
            #pragma unroll
            for (int r = 0; r < 4; ++r)
                p[kt][r] = exp2f(sacc[kt][r] - mrun[r]);
        #pragma unroll
        for (int r = 0; r < 4; ++r)
            rsum[r] = (p[0][r] + p[1][r]) + (p[2][r] + p[3][r]);
        #pragma unroll
        for (int r = 0; r < 4; ++r) {
            #pragma unroll
            for (int m = 1; m < 16; m <<= 1)
                rsum[r] += __shfl_xor(rsum[r], m, 64);
            lrun[r] = lrun[r] * sc[r] + rsum[r];
        }
        #pragma unroll
        for (int ht = 0; ht < 4; ++ht)
            #pragma unroll
            for (int r = 0; r < 4; ++r)
                O[ht][r] *= sc[r];

        // P -> LDS (bf16), then reload as PV A-fragments
        #pragma unroll
        for (int kt = 0; kt < 4; ++kt)
            #pragma unroll
            for (int r = 0; r < 4; ++r)
                plds[wv][lg * 4 + r][kt * 16 + lr] = f2bf(p[kt][r]);

        s8v pa0 = *(const s8v*)&plds[wv][lr][lg * 8];
        s8v pa1 = *(const s8v*)&plds[wv][lr][32 + lg * 8];

        #pragma unroll
        for (int ht = 0; ht < 4; ++ht) {
            O[ht] = __builtin_amdgcn_mfma_f32_16x16x32_bf16(pa0, vf0[ht], O[ht], 0, 0, 0);
            O[ht] = __builtin_amdgcn_mfma_f32_16x16x32_bf16(pa1, vf1[ht], O[ht], 0, 0, 0);
        }
    }

    // epilogue: out[b][q][h] fp32, normalized
    #pragma unroll
    for (int ht = 0; ht < 4; ++ht) {
        #pragma unroll
        for (int r = 0; r < 4; ++r) {
            const int row = qbase + lg * 4 + r;
            out[((size_t)b * 2048 + row) * 64 + ht * 16 + lr] = O[ht][r] / lrun[r];
        }
    }
}

extern "C" void kernel_launch(void* const* d_in, const int* in_sizes, int n_in,
                              void* d_out, int out_size, void* d_ws, size_t ws_size,
                              hipStream_t stream) {
    const float* x = (const float*)d_in[0];
    const float* w = (const float*)d_in[1];
    uint16_t* qw = (uint16_t*)d_ws;                 // 16384*64 bf16 = 2 MB
    uint16_t* kw = qw + (size_t)16384 * 64;         // 2 MB
    uint16_t* vw = kw + (size_t)16384 * 64;         // 2 MB (V transposed [b][h][s])
    float* out = (float*)d_out;

    qkv_proj<<<256, 256, 0, stream>>>(x, w, qw, kw, vw);
    attn<<<256, 256, 0, stream>>>(qw, kw, vw, out);
}

// Round 2
// 150.250 us; speedup vs baseline: 1.0704x; 1.0704x over previous
//
#include <hip/hip_runtime.h>
#include <hip/hip_bf16.h>
#include <stdint.h>

typedef short s8v __attribute__((ext_vector_type(8)));   // 8 bf16 (4 VGPRs)
typedef float f4v __attribute__((ext_vector_type(4)));   // MFMA C/D

static __device__ __forceinline__ uint16_t f2bf(float f) {
    union { float f; uint32_t u; } v; v.f = f;
    uint32_t r = v.u + 0x7fffu + ((v.u >> 16) & 1u);
    return (uint16_t)(r >> 16);
}

// ---------------------------------------------------------------------------
// Kernel 0: weight transpose+convert.  w[3][512][64] fp32 -> wt[192][512] bf16
//   wt[p*64+h][k] = w[p][k][h] * (p==0 ? log2e/8 : 1)
// 24 blocks (p x kb64) x 256 threads, LDS transpose.
// ---------------------------------------------------------------------------
__global__ __launch_bounds__(256) void wtrans(const float* __restrict__ w,
                                              uint16_t* __restrict__ wt) {
    __shared__ uint16_t lds[64][72];
    const int tid = threadIdx.x;
    const int p = blockIdx.x >> 3;
    const int kb = (blockIdx.x & 7) * 64;
    const float scale = (p == 0) ? 0.18033688011112042f : 1.0f;  // log2(e)/8

    #pragma unroll
    for (int i = 0; i < 16; ++i) {
        const int idx = i * 256 + tid;
        const int k = idx >> 6, h = idx & 63;
        lds[h][k] = f2bf(w[((size_t)(p * 512) + kb + k) * 64 + h] * scale);
    }
    __syncthreads();
    #pragma unroll
    for (int j = 0; j < 2; ++j) {
        const int c = j * 256 + tid;          // 512 chunks of 8
        const int h = c >> 3, kc = (c & 7) * 8;
        *(s8v*)(wt + (size_t)(p * 64 + h) * 512 + kb + kc) = *(const s8v*)&lds[h][kc];
    }
}

// ---------------------------------------------------------------------------
// Kernel 1: QKV projection.  x[16384][512] fp32 @ wt[192][512] bf16
//   -> Q [b][s][64] bf16 (pre-scaled), K [b][s][64] bf16, Vt [b][64][s] bf16
// 512 blocks (256 rowblocks x 2 col-halves) x 256 threads.
// Block tile 64 rows x 96 cols; wave = 16 rows x 96 cols; K-step 32.
// Register prefetch: issue next K-step loads before MFMAs of current.
// ---------------------------------------------------------------------------
__global__ __launch_bounds__(256) void qkv_proj(const float* __restrict__ x,
                                                const uint16_t* __restrict__ wt,
                                                uint16_t* __restrict__ qo,
                                                uint16_t* __restrict__ ko,
                                                uint16_t* __restrict__ vto) {
    __shared__ uint16_t xs[64][40];   // 80B rows, 16B aligned
    __shared__ uint16_t ws[96][40];

    const int tid  = threadIdx.x;
    const int lane = tid & 63;
    const int wv   = tid >> 6;
    const int row0 = (blockIdx.x >> 1) * 64;
    const int c0   = (blockIdx.x & 1) * 96;
    const int lr = lane & 15;
    const int lg = lane >> 4;

    f4v acc[6];
    #pragma unroll
    for (int i = 0; i < 6; ++i) acc[i] = (f4v){0.f, 0.f, 0.f, 0.f};

    const int xr = tid >> 2;            // 0..63
    const int xc = (tid & 3) * 8;       // 0,8,16,24
    const int w0row = tid >> 2,          w0kc = (tid & 3) * 8;
    const int w1row = (tid + 256) >> 2,  w1kc = (tid & 3) * 8;

    float4 xa, xb;
    s8v w0r, w1r;

    // prologue load kb=0
    {
        const float* xsrc = x + (size_t)(row0 + xr) * 512 + xc;
        xa = *(const float4*)xsrc;
        xb = *(const float4*)(xsrc + 4);
        w0r = *(const s8v*)(wt + (size_t)(c0 + w0row) * 512 + w0kc);
        if (tid < 128)
            w1r = *(const s8v*)(wt + (size_t)(c0 + w1row) * 512 + w1kc);
    }

    for (int kb = 0; kb < 512; kb += 32) {
        __syncthreads();
        // write staged regs -> LDS
        {
            s8v xv;
            xv[0] = (short)f2bf(xa.x); xv[1] = (short)f2bf(xa.y);
            xv[2] = (short)f2bf(xa.z); xv[3] = (short)f2bf(xa.w);
            xv[4] = (short)f2bf(xb.x); xv[5] = (short)f2bf(xb.y);
            xv[6] = (short)f2bf(xb.z); xv[7] = (short)f2bf(xb.w);
            *(s8v*)&xs[xr][xc] = xv;
            *(s8v*)&ws[w0row][w0kc] = w0r;
            if (tid < 128) *(s8v*)&ws[w1row][w1kc] = w1r;
        }
        __syncthreads();
        // issue next K-step loads (overlap with MFMAs below)
        if (kb + 32 < 512) {
            const float* xsrc = x + (size_t)(row0 + xr) * 512 + kb + 32 + xc;
            xa = *(const float4*)xsrc;
            xb = *(const float4*)(xsrc + 4);
            w0r = *(const s8v*)(wt + (size_t)(c0 + w0row) * 512 + kb + 32 + w0kc);
            if (tid < 128)
                w1r = *(const s8v*)(wt + (size_t)(c0 + w1row) * 512 + kb + 32 + w1kc);
        }
        s8v a = *(const s8v*)&xs[wv * 16 + lr][lg * 8];
        #pragma unroll
        for (int ct = 0; ct < 6; ++ct) {
            s8v bfr = *(const s8v*)&ws[ct * 16 + lr][lg * 8];
            acc[ct] = __builtin_amdgcn_mfma_f32_16x16x32_bf16(a, bfr, acc[ct], 0, 0, 0);
        }
    }

    // epilogue: D layout col = lane&15, row = (lane>>4)*4 + reg
    #pragma unroll
    for (int ct = 0; ct < 6; ++ct) {
        const int c = c0 + ct * 16 + lr;
        const int p = c >> 6, h = c & 63;
        #pragma unroll
        for (int r = 0; r < 4; ++r) {
            const int row = row0 + wv * 16 + lg * 4 + r;
            const uint16_t val = f2bf(acc[ct][r]);
            if (p == 0)      qo[(size_t)row * 64 + h] = val;
            else if (p == 1) ko[(size_t)row * 64 + h] = val;
            else {
                const int bb = row >> 11, s = row & 2047;
                vto[((size_t)bb * 64 + h) * 2048 + s] = val;
            }
        }
    }
}

// ---------------------------------------------------------------------------
// Kernel 2: flash attention with K-split.  Q,K [b][2048][64] bf16,
//   Vt [b][64][2048] bf16.  nsplit blocks per (b,qblk); each does 2048/nsplit
//   keys.  nsplit==1: write normalized out directly.  Else write unnormalized
//   O + (m,l) partials.
// ---------------------------------------------------------------------------
__global__ __launch_bounds__(256) void attn(const uint16_t* __restrict__ q,
                                            const uint16_t* __restrict__ k,
                                            const uint16_t* __restrict__ vt,
                                            float* __restrict__ opart,
                                            float2* __restrict__ ml,
                                            float* __restrict__ out,
                                            int nsplit) {
    __shared__ uint16_t plds[4][16][72];   // per-wave P^ tile [q][key]

    const int tid  = threadIdx.x;
    const int lane = tid & 63;
    const int wv   = tid >> 6;
    const int sp   = blockIdx.x % nsplit;
    const int bq   = blockIdx.x / nsplit;
    const int b    = bq >> 5;
    const int qblk = bq & 31;
    const int qbase = qblk * 64 + wv * 16;
    const int kspan = 2048 / nsplit;
    const int k0 = sp * kspan, kend = k0 + kspan;

    const uint16_t* qb = q  + (size_t)b * 2048 * 64;
    const uint16_t* kp = k  + (size_t)b * 2048 * 64;
    const uint16_t* vb = vt + (size_t)b * 64 * 2048;

    const int lr = lane & 15;
    const int lg = lane >> 4;

    s8v a0 = *(const s8v*)(qb + (size_t)(qbase + lr) * 64 + lg * 8);
    s8v a1 = *(const s8v*)(qb + (size_t)(qbase + lr) * 64 + 32 + lg * 8);

    f4v O[4];
    #pragma unroll
    for (int ht = 0; ht < 4; ++ht) O[ht] = (f4v){0.f, 0.f, 0.f, 0.f};
    float mrun[4], lrun[4];
    #pragma unroll
    for (int r = 0; r < 4; ++r) { mrun[r] = -3.0e38f; lrun[r] = 0.f; }

    s8v kf0[4], kf1[4];
    #pragma unroll
    for (int kt = 0; kt < 4; ++kt) {
        const uint16_t* kr = kp + (size_t)(k0 + kt * 16 + lr) * 64 + lg * 8;
        kf0[kt] = *(const s8v*)kr;
        kf1[kt] = *(const s8v*)(kr + 32);
    }

    for (int kb2 = k0; kb2 < kend; kb2 += 64) {
        s8v vf0[4], vf1[4];
        #pragma unroll
        for (int ht = 0; ht < 4; ++ht) {
            const uint16_t* vr = vb + (size_t)(ht * 16 + lr) * 2048 + kb2 + lg * 8;
            vf0[ht] = *(const s8v*)vr;
            vf1[ht] = *(const s8v*)(vr + 32);
        }

        f4v sacc[4];
        #pragma unroll
        for (int kt = 0; kt < 4; ++kt) {
            f4v z = (f4v){0.f, 0.f, 0.f, 0.f};
            z = __builtin_amdgcn_mfma_f32_16x16x32_bf16(a0, kf0[kt], z, 0, 0, 0);
            sacc[kt] = __builtin_amdgcn_mfma_f32_16x16x32_bf16(a1, kf1[kt], z, 0, 0, 0);
        }

        if (kb2 + 64 < kend) {
            #pragma unroll
            for (int kt = 0; kt < 4; ++kt) {
                const uint16_t* kr = kp + (size_t)(kb2 + 64 + kt * 16 + lr) * 64 + lg * 8;
                kf0[kt] = *(const s8v*)kr;
                kf1[kt] = *(const s8v*)(kr + 32);
            }
        }

        float rmax[4];
        #pragma unroll
        for (int r = 0; r < 4; ++r)
            rmax[r] = fmaxf(fmaxf(sacc[0][r], sacc[1][r]), fmaxf(sacc[2][r], sacc[3][r]));
        #pragma unroll
        for (int r = 0; r < 4; ++r) {
            #pragma unroll
            for (int m = 1; m < 16; m <<= 1)
                rmax[r] = fmaxf(rmax[r], __shfl_xor(rmax[r], m, 64));
        }
        float sc[4];
        #pragma unroll
        for (int r = 0; r < 4; ++r) {
            const float mn = fmaxf(mrun[r], rmax[r]);
            sc[r] = exp2f(mrun[r] - mn);
            mrun[r] = mn;
        }
        float p[4][4], rsum[4];
        #pragma unroll
        for (int kt = 0; kt < 4; ++kt)
            #pragma unroll
            for (int r = 0; r < 4; ++r)
                p[kt][r] = exp2f(sacc[kt][r] - mrun[r]);
        #pragma unroll
        for (int r = 0; r < 4; ++r)
            rsum[r] = (p[0][r] + p[1][r]) + (p[2][r] + p[3][r]);
        #pragma unroll
        for (int r = 0; r < 4; ++r) {
            #pragma unroll
            for (int m = 1; m < 16; m <<= 1)
                rsum[r] += __shfl_xor(rsum[r], m, 64);
            lrun[r] = lrun[r] * sc[r] + rsum[r];
        }
        #pragma unroll
        for (int ht = 0; ht < 4; ++ht)
            #pragma unroll
            for (int r = 0; r < 4; ++r)
                O[ht][r] *= sc[r];

        #pragma unroll
        for (int kt = 0; kt < 4; ++kt)
            #pragma unroll
            for (int r = 0; r < 4; ++r)
                plds[wv][lg * 4 + r][kt * 16 + lr] = f2bf(p[kt][r]);

        s8v pa0 = *(const s8v*)&plds[wv][lr][lg * 8];
        s8v pa1 = *(const s8v*)&plds[wv][lr][32 + lg * 8];

        #pragma unroll
        for (int ht = 0; ht < 4; ++ht) {
            O[ht] = __builtin_amdgcn_mfma_f32_16x16x32_bf16(pa0, vf0[ht], O[ht], 0, 0, 0);
            O[ht] = __builtin_amdgcn_mfma_f32_16x16x32_bf16(pa1, vf1[ht], O[ht], 0, 0, 0);
        }
    }

    if (nsplit == 1) {
        #pragma unroll
        for (int ht = 0; ht < 4; ++ht)
            #pragma unroll
            for (int r = 0; r < 4; ++r) {
                const int row = qbase + lg * 4 + r;
                out[((size_t)b * 2048 + row) * 64 + ht * 16 + lr] = O[ht][r] / lrun[r];
            }
    } else {
        #pragma unroll
        for (int ht = 0; ht < 4; ++ht)
            #pragma unroll
            for (int r = 0; r < 4; ++r) {
                const size_t grow = (size_t)b * 2048 + qbase + lg * 4 + r;
                opart[((size_t)sp * 16384 + grow) * 64 + ht * 16 + lr] = O[ht][r];
            }
        if (lr == 0) {
            #pragma unroll
            for (int r = 0; r < 4; ++r) {
                const size_t grow = (size_t)b * 2048 + qbase + lg * 4 + r;
                ml[(size_t)sp * 16384 + grow] = make_float2(mrun[r], lrun[r]);
            }
        }
    }
}

// ---------------------------------------------------------------------------
// Kernel 3: combine 4 K-split partials -> out fp32.
// 1024 blocks x 256 threads; thread = one float4 of output.
// ---------------------------------------------------------------------------
__global__ __launch_bounds__(256) void combine(const float* __restrict__ opart,
                                               const float2* __restrict__ ml,
                                               float* __restrict__ out) {
    const int idx = blockIdx.x * 256 + threadIdx.x;   // 262144 = 16384*16
    const int row = idx >> 4;
    const int hq = (idx & 15) * 4;

    const float2 m0 = ml[row];
    const float2 m1 = ml[16384 + row];
    const float2 m2 = ml[2 * 16384 + row];
    const float2 m3 = ml[3 * 16384 + row];
    const float M = fmaxf(fmaxf(m0.x, m1.x), fmaxf(m2.x, m3.x));
    const float w0 = exp2f(m0.x - M), w1 = exp2f(m1.x - M);
    const float w2 = exp2f(m2.x - M), w3 = exp2f(m3.x - M);
    const float inv = 1.0f / (w0 * m0.y + w1 * m1.y + w2 * m2.y + w3 * m3.y);

    const float4 o0 = *(const float4*)(opart + ((size_t)0 * 16384 + row) * 64 + hq);
    const float4 o1 = *(const float4*)(opart + ((size_t)1 * 16384 + row) * 64 + hq);
    const float4 o2 = *(const float4*)(opart + ((size_t)2 * 16384 + row) * 64 + hq);
    const float4 o3 = *(const float4*)(opart + ((size_t)3 * 16384 + row) * 64 + hq);

    float4 res;
    res.x = (w0 * o0.x + w1 * o1.x + w2 * o2.x + w3 * o3.x) * inv;
    res.y = (w0 * o0.y + w1 * o1.y + w2 * o2.y + w3 * o3.y) * inv;
    res.z = (w0 * o0.z + w1 * o1.z + w2 * o2.z + w3 * o3.z) * inv;
    res.w = (w0 * o0.w + w1 * o1.w + w2 * o2.w + w3 * o3.w) * inv;
    *(float4*)(out + (size_t)row * 64 + hq) = res;
}

extern "C" void kernel_launch(void* const* d_in, const int* in_sizes, int n_in,
                              void* d_out, int out_size, void* d_ws, size_t ws_size,
                              hipStream_t stream) {
    const float* x = (const float*)d_in[0];
    const float* w = (const float*)d_in[1];
    char* ws = (char*)d_ws;
    uint16_t* qw = (uint16_t*)(ws);                  // 2 MB
    uint16_t* kw = (uint16_t*)(ws + 2097152);        // 2 MB
    uint16_t* vw = (uint16_t*)(ws + 4194304);        // 2 MB  (V^T [b][h][s])
    uint16_t* wt = (uint16_t*)(ws + 6291456);        // 192 KB (w^T bf16, scaled)
    float*  opart = (float*)(ws + 6488064);          // 16 MB (4 splits)
    float2* ml    = (float2*)(ws + 23265280);        // 512 KB
    float* out = (float*)d_out;

    const int nsplit = (ws_size >= 23789568) ? 4 : 1;

    wtrans<<<24, 256, 0, stream>>>(w, wt);
    qkv_proj<<<512, 256, 0, stream>>>(x, wt, qw, kw, vw);
    attn<<<256 * nsplit, 256, 0, stream>>>(qw, kw, vw, opart, ml, out, nsplit);
    if (nsplit > 1) combine<<<1024, 256, 0, stream>>>(opart, ml, out);
}